// Round 4
// baseline (618.132 us; speedup 1.0000x reference)
//
#include <hip/hip_runtime.h>

#define LATENT 40
#define NUM_FLOWS 30
#define G 5                       // flows per prefetch group (800B contiguous per elem)
#define NGROUPS (NUM_FLOWS / G)   // 6

typedef float f32x4 __attribute__((ext_vector_type(4)));

#define NTL4(p) __builtin_nontemporal_load((const f32x4*)(p))
#define NTL1(p) __builtin_nontemporal_load(p)

// 8 lanes per batch element; lane idx owns floats [4idx,4idx+4) + 32+idx.
// Dot products xor-reduce across the 8-lane group. z stays in registers.
//
// R4 vs R3 (611.9 us, kernel ~230 us reconstructed = 45% of achievable BW):
//  THEORY: per-flow loads are 160B chunks at 4800B stride -> ~65K concurrent
//  DRAM streams advancing 160B/touch -> row-miss on nearly every access
//  (fills doing sequential writes hit 6.6 TB/s; we hit ~2.8).
//  FIX: group G=5 flows (contiguous 800B/elem window) and issue the whole
//  next group's 20 loads as ONE volley (ping-pong register sets a/b), so the
//  DRAM row opened for an elem's window is reused 5x in quick succession.
//  Same arithmetic as R3 (tanhf precision-critical; __logf safe).
#define STAGE(S, g0) do {                                                     \
    const float* wg = wrow + (g0) * G * LATENT;                               \
    const float* ug = urow + (g0) * G * LATENT;                               \
    _Pragma("unroll")                                                         \
    for (int s = 0; s < G; ++s) {                                             \
        wA_##S[s] = NTL4(wg + s * LATENT + 4 * idx);                          \
        wt_##S[s] = NTL1(wg + s * LATENT + 32 + idx);                         \
    }                                                                         \
    _Pragma("unroll")                                                         \
    for (int s = 0; s < G; ++s) {                                             \
        uA_##S[s] = NTL4(ug + s * LATENT + 4 * idx);                          \
        ut_##S[s] = NTL1(ug + s * LATENT + 32 + idx);                         \
    }                                                                         \
} while (0)

#define COMPUTE(S, g0) do {                                                   \
    _Pragma("unroll")                                                         \
    for (int s = 0; s < G; ++s) {                                             \
        const int i = (g0) * G + s;                                           \
        f32x4 wA = wA_##S[s]; float wt = wt_##S[s];                           \
        f32x4 uA = uA_##S[s]; float ut = ut_##S[s];                           \
        float s_wz = wA.x*zA.x + wA.y*zA.y + wA.z*zA.z + wA.w*zA.w + wt*zt;   \
        float s_wu = wA.x*uA.x + wA.y*uA.y + wA.z*uA.z + wA.w*uA.w + wt*ut;   \
        if (idx == (i >> 2)) {                                                \
            const int c = i & 3;                                              \
            s_wz += (c==0) ? bv0 : (c==1) ? bv1 : (c==2) ? bv2 : bv3;         \
        }                                                                     \
        s_wz += __shfl_xor(s_wz, 1); s_wu += __shfl_xor(s_wu, 1);             \
        s_wz += __shfl_xor(s_wz, 2); s_wu += __shfl_xor(s_wu, 2);             \
        s_wz += __shfl_xor(s_wz, 4); s_wu += __shfl_xor(s_wu, 4);             \
        float t = tanhf(s_wz);  /* precision-critical: feeds 1/det-amplified ladj */ \
        zA.x += uA.x * t; zA.y += uA.y * t; zA.z += uA.z * t; zA.w += uA.w * t; \
        zt   += ut * t;                                                       \
        float det = fmaf(1.0f - t * t, s_wu, 1.0f);                           \
        ladj += __logf(fabsf(det));  /* native log: error not amplified */    \
    }                                                                         \
} while (0)

__global__ __launch_bounds__(256) void nf_kernel(
    const float* __restrict__ z_k,   // [B, 40]
    const float* __restrict__ w,     // [B, 1200]
    const float* __restrict__ u,     // [B, 1200]
    const float* __restrict__ bias,  // [B, 30]
    float* __restrict__ out,         // [B*40] z_out then [B] sum_ladj
    int B)
{
    int tid  = blockIdx.x * 256 + threadIdx.x;
    int elem = tid >> 3;
    int idx  = tid & 7;
    if (elem >= B) return;

    const float* zrow = z_k + (size_t)elem * LATENT;
    f32x4 zA = NTL4(zrow + 4 * idx);
    float zt = NTL1(zrow + 32 + idx);

    const float* wrow = w + (size_t)elem * (NUM_FLOWS * LATENT);
    const float* urow = u + (size_t)elem * (NUM_FLOWS * LATENT);

    // Preload all 30 b values: lane idx holds b[4idx..4idx+4) (lane 7: 2 valid).
    const float* brow = bias + (size_t)elem * NUM_FLOWS;
    float bv0 = 0.f, bv1 = 0.f, bv2 = 0.f, bv3 = 0.f;
    {
        int base = 4 * idx;
        bv0 = brow[base];
        bv1 = brow[base + 1];                        // base+1 <= 29, always valid
        if (base + 2 < NUM_FLOWS) bv2 = brow[base + 2];
        if (base + 3 < NUM_FLOWS) bv3 = brow[base + 3];
    }

    // Ping-pong register sets: while computing one group's 5 flows, the other
    // set's 20 loads (one tight volley per group) are in flight.
    f32x4 wA_a[G], uA_a[G], wA_b[G], uA_b[G];
    float wt_a[G], ut_a[G], wt_b[G], ut_b[G];

    float ladj = 0.f;

    STAGE(a, 0);
    STAGE(b, 1);
    COMPUTE(a, 0);
    STAGE(a, 2);
    COMPUTE(b, 1);
    STAGE(b, 3);
    COMPUTE(a, 2);
    STAGE(a, 4);
    COMPUTE(b, 3);
    STAGE(b, 5);
    COMPUTE(a, 4);
    COMPUTE(b, 5);

    float* zout = out + (size_t)elem * LATENT;
    __builtin_nontemporal_store(zA, (f32x4*)(zout + 4 * idx));
    __builtin_nontemporal_store(zt, zout + 32 + idx);
    if (idx == 0) __builtin_nontemporal_store(ladj, out + (size_t)B * LATENT + elem);
}

extern "C" void kernel_launch(void* const* d_in, const int* in_sizes, int n_in,
                              void* d_out, int out_size, void* d_ws, size_t ws_size,
                              hipStream_t stream) {
    const float* z_k  = (const float*)d_in[0];
    const float* w    = (const float*)d_in[1];
    const float* u    = (const float*)d_in[2];
    const float* bias = (const float*)d_in[3];
    float* out = (float*)d_out;

    int B = in_sizes[0] / LATENT;           // 65536
    int threads = B * 8;                    // 8 lanes per batch element
    int block = 256;
    int grid = (threads + block - 1) / block;
    nf_kernel<<<grid, block, 0, stream>>>(z_k, w, u, bias, out, B);
}